// Round 1
// baseline (2944.316 us; speedup 1.0000x reference)
//
#include <hip/hip_runtime.h>

#define EPS 1e-5f
#define SLOPE 0.01f

// Generic submanifold-conv-as-gather-GEMM.
// Block: 256 threads, computes 64 output rows x 64 output channels.
// out[n,d] = sum_k sum_c in[nbr[k,n], c] * W[k,c,d]   (nbr==tableN -> zero row)
// Optional: += skip, LeakyReLU, per-channel sum/sumsq atomics for BN.
__global__ __launch_bounds__(256, 4)
void subm_conv_kernel(const float* __restrict__ in, int tableN, int Cin,
                      const int* __restrict__ nbr, int K, int Nout,
                      const float* __restrict__ W,
                      const float* __restrict__ skip,
                      float* __restrict__ out,
                      float* __restrict__ stats,   // [64 sum][64 sumsq] or null
                      int do_lrelu)
{
    __shared__ __align__(16) float As[64][72];  // 72: pad so 4 ty-rows hit distinct banks
    __shared__ __align__(16) float Ws[64][64];  // [c][d]: broadcast reads, conflict-free
    __shared__ int idxs[64];

    const int t  = threadIdx.x;
    const int tx = t & 15;          // output channel group
    const int ty = t >> 4;          // output row group
    const int row0 = blockIdx.x * 64;

    float acc[4][4];
#pragma unroll
    for (int i = 0; i < 4; ++i)
#pragma unroll
        for (int j = 0; j < 4; ++j) acc[i][j] = 0.f;

    const int nchunk = Cin >> 6;    // 1 (C=64) or 2 (C=128)

    for (int k = 0; k < K; ++k) {
        // indices for this offset. Hazard-safe: previous gather's idxs reads all
        // completed before the barrier that preceded the previous compute phase.
        if (t < 64) {
            int r = row0 + t;
            idxs[t] = (r < Nout) ? nbr[k * Nout + r] : tableN;
        }
        for (int cc = 0; cc < nchunk; ++cc) {
            __syncthreads();   // previous compute done -> safe to overwrite As/Ws (also publishes idxs)
            // ---- gather A tile: 64 rows x 64 channels (float4, coalesced 64B/row-segment)
#pragma unroll
            for (int i = 0; i < 4; ++i) {
                int f4 = t + 256 * i;          // 0..1023
                int r  = f4 >> 4;
                int c4 = (f4 & 15) << 2;
                int src = idxs[r];
                float4 v;
                if (src < tableN) {
                    v = *(const float4*)(in + (size_t)src * Cin + cc * 64 + c4);
                } else {
                    v = make_float4(0.f, 0.f, 0.f, 0.f);
                }
                *(float4*)&As[r][c4] = v;
            }
            // ---- load W chunk: W[k, cc*64 + c, d], contiguous 64x64 block
            const float* Wk = W + ((size_t)k * Cin + cc * 64) * 64;
#pragma unroll
            for (int i = 0; i < 4; ++i) {
                int f4 = t + 256 * i;
                int r  = f4 >> 4;
                int c4 = (f4 & 15) << 2;
                *(float4*)&Ws[r][c4] = *(const float4*)(Wk + r * 64 + c4);
            }
            __syncthreads();
            // ---- 64-deep FMA microkernel, 4x4 outputs/thread
#pragma unroll
            for (int c4 = 0; c4 < 16; ++c4) {
                const int cb = c4 << 2;
                float4 A0 = *(const float4*)&As[ty     ][cb];
                float4 A1 = *(const float4*)&As[ty + 16][cb];
                float4 A2 = *(const float4*)&As[ty + 32][cb];
                float4 A3 = *(const float4*)&As[ty + 48][cb];
                float ar[4][4] = {
                    {A0.x, A0.y, A0.z, A0.w},
                    {A1.x, A1.y, A1.z, A1.w},
                    {A2.x, A2.y, A2.z, A2.w},
                    {A3.x, A3.y, A3.z, A3.w},
                };
#pragma unroll
                for (int m = 0; m < 4; ++m) {
                    const int c = cb + m;
                    float b0 = Ws[c][tx];
                    float b1 = Ws[c][tx + 16];
                    float b2 = Ws[c][tx + 32];
                    float b3 = Ws[c][tx + 48];
#pragma unroll
                    for (int i = 0; i < 4; ++i) {
                        acc[i][0] = fmaf(ar[i][m], b0, acc[i][0]);
                        acc[i][1] = fmaf(ar[i][m], b1, acc[i][1]);
                        acc[i][2] = fmaf(ar[i][m], b2, acc[i][2]);
                        acc[i][3] = fmaf(ar[i][m], b3, acc[i][3]);
                    }
                }
            }
        }
    }

    // ---- epilogue: skip add, LeakyReLU, store, per-channel partial stats
    float psum[4], psq[4];
#pragma unroll
    for (int j = 0; j < 4; ++j) { psum[j] = 0.f; psq[j] = 0.f; }

#pragma unroll
    for (int i = 0; i < 4; ++i) {
        int r = row0 + ty + 16 * i;
        if (r < Nout) {
#pragma unroll
            for (int j = 0; j < 4; ++j) {
                int d = tx + 16 * j;
                float v = acc[i][j];
                if (skip) v += skip[(size_t)r * 64 + d];
                if (do_lrelu) v = (v >= 0.f) ? v : SLOPE * v;
                out[(size_t)r * 64 + d] = v;
                psum[j] += v;
                psq[j]  += v * v;
            }
        }
    }

    if (stats) {
        __syncthreads();               // done reading As for compute
#pragma unroll
        for (int j = 0; j < 4; ++j) {
            int c = tx + 16 * j;
            As[c][ty]      = psum[j];
            As[c][16 + ty] = psq[j];
        }
        __syncthreads();
        if (t < 64) {
            float s = 0.f, q = 0.f;
#pragma unroll
            for (int u = 0; u < 16; ++u) { s += As[t][u]; q += As[t][16 + u]; }
            atomicAdd(&stats[t], s);
            atomicAdd(&stats[64 + t], q);
        }
    }
}

// BatchNorm apply (training-mode batch stats), elementwise in-place capable.
__global__ __launch_bounds__(256)
void bn_apply_kernel(const float* __restrict__ buf, int N,
                     const float* __restrict__ stats,
                     const float* __restrict__ gamma,
                     const float* __restrict__ beta,
                     float invN, float* __restrict__ outbuf)
{
    __shared__ float sc[64], sh[64];
    int t = threadIdx.x;
    if (t < 64) {
        float mean = stats[t] * invN;
        float var  = stats[64 + t] * invN - mean * mean;
        float s    = gamma[t] * rsqrtf(var + EPS);
        sc[t] = s;
        sh[t] = beta[t] - mean * s;
    }
    __syncthreads();
    size_t total4 = (size_t)N * 16;   // N*64 floats / 4
    for (size_t i = (size_t)blockIdx.x * blockDim.x + t; i < total4;
         i += (size_t)gridDim.x * blockDim.x) {
        float4 v = ((const float4*)buf)[i];
        int c0 = ((int)(i & 15)) << 2;
        v.x = v.x * sc[c0]     + sh[c0];
        v.y = v.y * sc[c0 + 1] + sh[c0 + 1];
        v.z = v.z * sc[c0 + 2] + sh[c0 + 2];
        v.w = v.w * sc[c0 + 3] + sh[c0 + 3];
        ((float4*)outbuf)[i] = v;
    }
}

extern "C" void kernel_launch(void* const* d_in, const int* in_sizes, int n_in,
                              void* d_out, int out_size, void* d_ws, size_t ws_size,
                              hipStream_t stream) {
    const float* x_feats   = (const float*)d_in[0];
    const float* skip      = (const float*)d_in[1];
    const int*   nbr_trans = (const int*)d_in[2];
    const int*   nbr_up    = (const int*)d_in[3];
    const int*   nbr1      = (const int*)d_in[4];
    const int*   nbr2      = (const int*)d_in[5];
    const int*   nbr3      = (const int*)d_in[6];
    const float* W_trans   = (const float*)d_in[7];
    const float* W_up      = (const float*)d_in[8];
    const float* W1        = (const float*)d_in[9];
    const float* W2        = (const float*)d_in[10];
    const float* W3        = (const float*)d_in[11];
    const float* gamma_t   = (const float*)d_in[12];
    const float* beta_t    = (const float*)d_in[13];
    const float* gamma1    = (const float*)d_in[14];
    const float* beta1     = (const float*)d_in[15];
    const float* gamma2    = (const float*)d_in[16];
    const float* beta2     = (const float*)d_in[17];
    const float* gamma3    = (const float*)d_in[18];
    const float* beta3     = (const float*)d_in[19];

    const int Nin  = in_sizes[0] / 128;   // 80000
    const int Nout = in_sizes[1] / 64;    // 200000

    // Workspace layout (fp32): t[Nin*64] | u[Nout*64] | a[Nout*64] | stats[4*128]
    float* t_buf = (float*)d_ws;
    float* u_buf = t_buf + (size_t)Nin * 64;
    float* a_buf = u_buf + (size_t)Nout * 64;
    float* stats = a_buf + (size_t)Nout * 64;
    float* out   = (float*)d_out;

    hipMemsetAsync(stats, 0, 4 * 128 * sizeof(float), stream);

    dim3 blk(256);
    const int gIn  = (Nin  + 63) / 64;
    const int gOut = (Nout + 63) / 64;
    const float invNin  = 1.f / (float)Nin;
    const float invNout = 1.f / (float)Nout;

    // trans_dilao: SubMConv(Cin=128,K=27) + LeakyReLU + BN
    subm_conv_kernel<<<gIn, blk, 0, stream>>>(x_feats, Nin, 128, nbr_trans, 27, Nin,
                                              W_trans, nullptr, t_buf, stats + 0, 1);
    bn_apply_kernel<<<1024, blk, 0, stream>>>(t_buf, Nin, stats + 0, gamma_t, beta_t,
                                              invNin, t_buf);
    // SparseInverseConv (K=27) + skip residual (no act/bn)
    subm_conv_kernel<<<gOut, blk, 0, stream>>>(t_buf, Nin, 64, nbr_up, 27, Nout,
                                               W_up, skip, u_buf, nullptr, 0);
    // conv1 (K=9) + LeakyReLU + BN
    subm_conv_kernel<<<gOut, blk, 0, stream>>>(u_buf, Nout, 64, nbr1, 9, Nout,
                                               W1, nullptr, a_buf, stats + 128, 1);
    bn_apply_kernel<<<2048, blk, 0, stream>>>(a_buf, Nout, stats + 128, gamma1, beta1,
                                              invNout, a_buf);
    // conv2 (K=9) + LeakyReLU + BN   (reuse u_buf)
    subm_conv_kernel<<<gOut, blk, 0, stream>>>(a_buf, Nout, 64, nbr2, 9, Nout,
                                               W2, nullptr, u_buf, stats + 256, 1);
    bn_apply_kernel<<<2048, blk, 0, stream>>>(u_buf, Nout, stats + 256, gamma2, beta2,
                                              invNout, u_buf);
    // conv3 (K=27) + LeakyReLU + BN -> d_out (raw into d_out, normalize in place)
    subm_conv_kernel<<<gOut, blk, 0, stream>>>(u_buf, Nout, 64, nbr3, 27, Nout,
                                               W3, nullptr, out, stats + 384, 1);
    bn_apply_kernel<<<2048, blk, 0, stream>>>(out, Nout, stats + 384, gamma3, beta3,
                                              invNout, out);
}

// Round 2
// 1065.754 us; speedup vs baseline: 2.7627x; 2.7627x over previous
//
#include <hip/hip_runtime.h>

#define EPS 1e-5f
#define SLOPE 0.01f

typedef __attribute__((ext_vector_type(8))) short bf16x8;
typedef __attribute__((ext_vector_type(4))) float f32x4;

static __device__ __forceinline__ unsigned short f2bf(float f) {
    unsigned u = __float_as_uint(f);
    u += 0x7fff + ((u >> 16) & 1);          // round-to-nearest-even
    return (unsigned short)(u >> 16);
}
static __device__ __forceinline__ float bf2f(unsigned short h) {
    return __uint_as_float(((unsigned)h) << 16);
}

// ---------------------------------------------------------------------------
// Gather-GEMM submanifold conv, bf16 MFMA (16x16x32), fp32 accumulate.
// Block = 256 threads (4 waves). Tile = ROWS x 64 output. Per k-offset:
// stage ROWS x 64ch bf16 gathered rows + 64x64 W chunk in LDS, MFMA.
// LDS rows padded to 72 bf16: frag-read banks 4(m+a)+j -> conflict-free.
template<int ROWS>
__global__ __launch_bounds__(256, 3)
void conv_mfma(const unsigned short* __restrict__ in, int tableN, int Cin,
               const int* __restrict__ nbr, int K, int Nout,
               const unsigned short* __restrict__ Wt,   // [K][64][Cin] bf16
               const float* __restrict__ skip,
               unsigned short* __restrict__ out_bf,
               float* __restrict__ out_f32,
               float* __restrict__ stats, int do_lrelu)
{
    constexpr int RT = ROWS / 64;            // row-tiles (16 rows) per wave
    __shared__ unsigned short As[ROWS][72];
    __shared__ unsigned short Bs[64][72];
    __shared__ int idxs[ROWS];
    __shared__ float red[2][64][4];

    const int t    = threadIdx.x;
    const int lane = t & 63;
    const int w    = t >> 6;
    const int q    = lane >> 4;              // quad 0..3
    const int m    = lane & 15;
    const int row0 = blockIdx.x * ROWS;
    const int nchunk = Cin >> 6;

    f32x4 acc[RT][4];
#pragma unroll
    for (int rt = 0; rt < RT; ++rt)
#pragma unroll
        for (int ct = 0; ct < 4; ++ct) acc[rt][ct] = (f32x4){0.f, 0.f, 0.f, 0.f};

    for (int k = 0; k < K; ++k) {
        // idxs last read before previous post-staging barrier; compute phase
        // doesn't touch idxs -> safe to overwrite here, published by next barrier.
        if (t < ROWS) {
            int r = row0 + t;
            idxs[t] = (r < Nout) ? nbr[(size_t)k * Nout + r] : tableN;
        }
        for (int cc = 0; cc < nchunk; ++cc) {
            __syncthreads();                 // prev compute done; publishes idxs
            // ---- gather A tile: 8 lanes per row, 16B atoms, coalesced 128B rows
#pragma unroll
            for (int i = 0; i < ROWS / 32; ++i) {
                int r = (t >> 3) + 32 * i;
                int a = t & 7;
                int src = idxs[r];
                int4 v = make_int4(0, 0, 0, 0);
                if (src < tableN)
                    v = *(const int4*)(in + (size_t)src * Cin + cc * 64 + a * 8);
                *(int4*)&As[r][a * 8] = v;
            }
            // ---- stage W chunk (already transposed [d][c], bf16)
#pragma unroll
            for (int i = 0; i < 2; ++i) {
                int d = (t >> 3) + 32 * i;
                int a = t & 7;
                *(int4*)&Bs[d][a * 8] =
                    *(const int4*)(Wt + ((size_t)k * 64 + d) * Cin + cc * 64 + a * 8);
            }
            __syncthreads();
            // ---- MFMA: A[m=lane&15][k=q*8+j], B[k=q*8+j][n=lane&15]
#pragma unroll
            for (int kk = 0; kk < 2; ++kk) {
                const int kb = kk * 32 + q * 8;
                bf16x8 af[RT], bfr[4];
#pragma unroll
                for (int rt = 0; rt < RT; ++rt)
                    af[rt] = *(const bf16x8*)&As[w * (RT * 16) + rt * 16 + m][kb];
#pragma unroll
                for (int ct = 0; ct < 4; ++ct)
                    bfr[ct] = *(const bf16x8*)&Bs[ct * 16 + m][kb];
#pragma unroll
                for (int rt = 0; rt < RT; ++rt)
#pragma unroll
                    for (int ct = 0; ct < 4; ++ct)
                        acc[rt][ct] = __builtin_amdgcn_mfma_f32_16x16x32_bf16(
                            af[rt], bfr[ct], acc[rt][ct], 0, 0, 0);
            }
        }
    }

    // ---- epilogue: C/D layout col=lane&15, row=q*4+reg (verified m89/m91)
    float psum[4] = {0.f, 0.f, 0.f, 0.f}, psq[4] = {0.f, 0.f, 0.f, 0.f};
#pragma unroll
    for (int rt = 0; rt < RT; ++rt) {
#pragma unroll
        for (int ct = 0; ct < 4; ++ct) {
            int col = ct * 16 + m;
#pragma unroll
            for (int reg = 0; reg < 4; ++reg) {
                int r = row0 + w * (RT * 16) + rt * 16 + q * 4 + reg;
                if (r < Nout) {
                    float v = acc[rt][ct][reg];
                    if (skip) v += skip[(size_t)r * 64 + col];
                    if (do_lrelu) v = (v >= 0.f) ? v : SLOPE * v;
                    if (out_bf) out_bf[(size_t)r * 64 + col] = f2bf(v);
                    else        out_f32[(size_t)r * 64 + col] = v;
                    psum[ct] += v;
                    psq[ct]  += v * v;
                }
            }
        }
    }

    if (stats) {
        // lanes m, m+16, m+32, m+48 share a channel -> shuffle reduce to q==0
#pragma unroll
        for (int ct = 0; ct < 4; ++ct) {
            psum[ct] += __shfl_down(psum[ct], 32);
            psum[ct] += __shfl_down(psum[ct], 16);
            psq[ct]  += __shfl_down(psq[ct], 32);
            psq[ct]  += __shfl_down(psq[ct], 16);
        }
        if (q == 0) {
#pragma unroll
            for (int ct = 0; ct < 4; ++ct) {
                red[0][ct * 16 + m][w] = psum[ct];
                red[1][ct * 16 + m][w] = psq[ct];
            }
        }
        __syncthreads();
        if (t < 64) {
            float s  = red[0][t][0] + red[0][t][1] + red[0][t][2] + red[0][t][3];
            float qq = red[1][t][0] + red[1][t][1] + red[1][t][2] + red[1][t][3];
            atomicAdd(&stats[t], s);
            atomicAdd(&stats[64 + t], qq);
        }
    }
}

// BN apply on bf16 buffer in-place (batch stats from fp32 accumulators).
__global__ __launch_bounds__(256)
void bn_apply_bf16(unsigned short* __restrict__ buf, size_t total8,
                   const float* __restrict__ stats,
                   const float* __restrict__ gamma,
                   const float* __restrict__ beta, float invN)
{
    __shared__ float sc[64], sh[64];
    int t = threadIdx.x;
    if (t < 64) {
        float mean = stats[t] * invN;
        float var  = stats[64 + t] * invN - mean * mean;
        float s    = gamma[t] * rsqrtf(var + EPS);
        sc[t] = s;
        sh[t] = beta[t] - mean * s;
    }
    __syncthreads();
    for (size_t i = (size_t)blockIdx.x * blockDim.x + t; i < total8;
         i += (size_t)gridDim.x * blockDim.x) {
        int4 v = ((const int4*)buf)[i];
        unsigned short* e = (unsigned short*)&v;
        int c0 = ((int)(i & 7)) << 3;
#pragma unroll
        for (int j = 0; j < 8; ++j)
            e[j] = f2bf(bf2f(e[j]) * sc[c0 + j] + sh[c0 + j]);
        ((int4*)buf)[i] = v;
    }
}

// BN apply fp32 in-place (final layer -> d_out).
__global__ __launch_bounds__(256)
void bn_apply_f32(float* __restrict__ buf, int N,
                  const float* __restrict__ stats,
                  const float* __restrict__ gamma,
                  const float* __restrict__ beta, float invN)
{
    __shared__ float sc[64], sh[64];
    int t = threadIdx.x;
    if (t < 64) {
        float mean = stats[t] * invN;
        float var  = stats[64 + t] * invN - mean * mean;
        float s    = gamma[t] * rsqrtf(var + EPS);
        sc[t] = s;
        sh[t] = beta[t] - mean * s;
    }
    __syncthreads();
    size_t total4 = (size_t)N * 16;
    for (size_t i = (size_t)blockIdx.x * blockDim.x + t; i < total4;
         i += (size_t)gridDim.x * blockDim.x) {
        float4 v = ((const float4*)buf)[i];
        int c0 = ((int)(i & 15)) << 2;
        v.x = v.x * sc[c0]     + sh[c0];
        v.y = v.y * sc[c0 + 1] + sh[c0 + 1];
        v.z = v.z * sc[c0 + 2] + sh[c0 + 2];
        v.w = v.w * sc[c0 + 3] + sh[c0 + 3];
        ((float4*)buf)[i] = v;
    }
}

// fp32 -> bf16 elementwise convert (x_feats).
__global__ __launch_bounds__(256)
void cvt_bf16(const float* __restrict__ in, unsigned short* __restrict__ out,
              size_t n4)
{
    for (size_t i = (size_t)blockIdx.x * blockDim.x + threadIdx.x; i < n4;
         i += (size_t)gridDim.x * blockDim.x) {
        float4 v = ((const float4*)in)[i];
        ushort4 o;
        o.x = f2bf(v.x); o.y = f2bf(v.y); o.z = f2bf(v.z); o.w = f2bf(v.w);
        ((ushort4*)out)[i] = o;
    }
}

// W[k][c][d] fp32 -> Wt[k][d][c] bf16 (coalesced writes, strided tiny reads).
__global__ __launch_bounds__(256)
void wt_cvt(const float* __restrict__ W, unsigned short* __restrict__ Wt,
            int K, int Cin)
{
    int total = K * Cin * 64;
    for (int e = blockIdx.x * blockDim.x + threadIdx.x; e < total;
         e += gridDim.x * blockDim.x) {
        int c = e % Cin;
        int rest = e / Cin;
        int d = rest & 63;
        int k = rest >> 6;
        Wt[e] = f2bf(W[((size_t)k * Cin + c) * 64 + d]);
    }
}

extern "C" void kernel_launch(void* const* d_in, const int* in_sizes, int n_in,
                              void* d_out, int out_size, void* d_ws, size_t ws_size,
                              hipStream_t stream) {
    const float* x_feats   = (const float*)d_in[0];
    const float* skip      = (const float*)d_in[1];
    const int*   nbr_trans = (const int*)d_in[2];
    const int*   nbr_up    = (const int*)d_in[3];
    const int*   nbr1      = (const int*)d_in[4];
    const int*   nbr2      = (const int*)d_in[5];
    const int*   nbr3      = (const int*)d_in[6];
    const float* W_trans   = (const float*)d_in[7];
    const float* W_up      = (const float*)d_in[8];
    const float* W1        = (const float*)d_in[9];
    const float* W2        = (const float*)d_in[10];
    const float* W3        = (const float*)d_in[11];
    const float* gamma_t   = (const float*)d_in[12];
    const float* beta_t    = (const float*)d_in[13];
    const float* gamma1    = (const float*)d_in[14];
    const float* beta1     = (const float*)d_in[15];
    const float* gamma2    = (const float*)d_in[16];
    const float* beta2     = (const float*)d_in[17];
    const float* gamma3    = (const float*)d_in[18];
    const float* beta3     = (const float*)d_in[19];

    const int Nin  = in_sizes[0] / 128;   // 80000
    const int Nout = in_sizes[1] / 64;    // 200000

    // ---- workspace layout (256B-aligned regions), ~109 MB total
    size_t off = 0;
    auto alloc = [&](size_t bytes) {
        void* p = (char*)d_ws + off;
        off = (off + bytes + 255) & ~(size_t)255;
        return p;
    };
    unsigned short* xb   = (unsigned short*)alloc((size_t)Nin * 128 * 2);
    unsigned short* tb   = (unsigned short*)alloc((size_t)Nin * 64 * 2);
    unsigned short* ub   = (unsigned short*)alloc((size_t)Nout * 64 * 2);
    unsigned short* ab   = (unsigned short*)alloc((size_t)Nout * 64 * 2);
    unsigned short* vb   = (unsigned short*)alloc((size_t)Nout * 64 * 2);
    unsigned short* wt_t = (unsigned short*)alloc((size_t)27 * 128 * 64 * 2);
    unsigned short* wt_u = (unsigned short*)alloc((size_t)27 * 64 * 64 * 2);
    unsigned short* wt1  = (unsigned short*)alloc((size_t)9 * 64 * 64 * 2);
    unsigned short* wt2  = (unsigned short*)alloc((size_t)9 * 64 * 64 * 2);
    unsigned short* wt3  = (unsigned short*)alloc((size_t)27 * 64 * 64 * 2);
    float* stats = (float*)alloc(512 * sizeof(float));
    float* out   = (float*)d_out;

    hipMemsetAsync(stats, 0, 512 * sizeof(float), stream);

    dim3 blk(256);
    const float invNin  = 1.f / (float)Nin;
    const float invNout = 1.f / (float)Nout;

    // ---- weight transpose+convert (tiny) and feature convert
    wt_cvt<<<864, blk, 0, stream>>>(W_trans, wt_t, 27, 128);
    wt_cvt<<<432, blk, 0, stream>>>(W_up,    wt_u, 27, 64);
    wt_cvt<<<144, blk, 0, stream>>>(W1,      wt1,  9,  64);
    wt_cvt<<<144, blk, 0, stream>>>(W2,      wt2,  9,  64);
    wt_cvt<<<432, blk, 0, stream>>>(W3,      wt3,  27, 64);
    cvt_bf16<<<2048, blk, 0, stream>>>(x_feats, xb, (size_t)Nin * 32);

    const int gIn  = (Nin  + 127) / 128;  // 625
    const int gOut = (Nout + 255) / 256;  // 782

    // trans_dilao: Cin=128, K=27 + LeakyReLU + BN
    conv_mfma<128><<<gIn, blk, 0, stream>>>(xb, Nin, 128, nbr_trans, 27, Nin,
                                            wt_t, nullptr, tb, nullptr, stats + 0, 1);
    bn_apply_bf16<<<1024, blk, 0, stream>>>(tb, (size_t)Nin * 8, stats + 0,
                                            gamma_t, beta_t, invNin);
    // SparseInverseConv K=27 + skip (no act/bn)
    conv_mfma<256><<<gOut, blk, 0, stream>>>(tb, Nin, 64, nbr_up, 27, Nout,
                                             wt_u, skip, ub, nullptr, nullptr, 0);
    // conv1 K=9 + LeakyReLU + BN
    conv_mfma<256><<<gOut, blk, 0, stream>>>(ub, Nout, 64, nbr1, 9, Nout,
                                             wt1, nullptr, ab, nullptr, stats + 128, 1);
    bn_apply_bf16<<<2048, blk, 0, stream>>>(ab, (size_t)Nout * 8, stats + 128,
                                            gamma1, beta1, invNout);
    // conv2 K=9 + LeakyReLU + BN
    conv_mfma<256><<<gOut, blk, 0, stream>>>(ab, Nout, 64, nbr2, 9, Nout,
                                             wt2, nullptr, vb, nullptr, stats + 256, 1);
    bn_apply_bf16<<<2048, blk, 0, stream>>>(vb, (size_t)Nout * 8, stats + 256,
                                            gamma2, beta2, invNout);
    // conv3 K=27 + LeakyReLU + BN -> d_out (fp32), normalize in place
    conv_mfma<256><<<gOut, blk, 0, stream>>>(vb, Nout, 64, nbr3, 27, Nout,
                                             wt3, nullptr, nullptr, out, stats + 384, 1);
    bn_apply_f32<<<2048, blk, 0, stream>>>(out, Nout, stats + 384,
                                           gamma3, beta3, invNout);
}

// Round 3
// 1058.087 us; speedup vs baseline: 2.7827x; 1.0072x over previous
//
#include <hip/hip_runtime.h>

#define EPS 1e-5f
#define SLOPE 0.01f

typedef __attribute__((ext_vector_type(8))) short bf16x8;
typedef __attribute__((ext_vector_type(4))) float f32x4;

static __device__ __forceinline__ unsigned short f2bf(float f) {
    unsigned u = __float_as_uint(f);
    u += 0x7fff + ((u >> 16) & 1);          // round-to-nearest-even
    return (unsigned short)(u >> 16);
}
static __device__ __forceinline__ float bf2f(unsigned short h) {
    return __uint_as_float(((unsigned)h) << 16);
}

// ---------------------------------------------------------------------------
// Gather-GEMM submanifold conv, bf16 MFMA 16x16x32, all-register (no LDS
// staging, no k-loop barriers). Each wave owns 64 rows x 64 cols:
//   A-frag: 4 lanes/row read one 64B segment of the gathered row (direct).
//   B-frag: direct from transposed weights Wt[k][d][c] (L2-resident).
// Software pipeline: idx 2 ahead, A/B fragments 1 ahead (Cin=64 only).
// NOTE: gather tables must tolerate reading row `tableN` (sentinel) -- all
// feature tables live in d_ws with space after them, result is masked to 0.
template<int K, int NCH>
__global__ __launch_bounds__(256, 2)
void conv_mfma(const unsigned short* __restrict__ in, int tableN,
               const int* __restrict__ nbr, int Nout,
               const unsigned short* __restrict__ Wt,   // [K][64][Cin] bf16
               const float* __restrict__ skip,
               unsigned short* __restrict__ out_bf,
               float* __restrict__ out_f32,
               float* __restrict__ stats, int do_lrelu)
{
    constexpr int Cin = NCH * 64;
    constexpr int KC  = NCH * 2;            // 32-channel MFMA k-steps per offset
    constexpr bool PF = (NCH == 1);         // deep prefetch only when regs allow

    __shared__ float red[2][64][4];

    const int t    = threadIdx.x;
    const int lane = t & 63;
    const int w    = t >> 6;
    const int q    = lane >> 4;             // quad 0..3
    const int m    = lane & 15;
    const int row0 = blockIdx.x * 256 + w * 64;   // this wave's 64 rows

    const bf16x8 ZV = {0, 0, 0, 0, 0, 0, 0, 0};

    f32x4 acc[4][4];
#pragma unroll
    for (int rt = 0; rt < 4; ++rt)
#pragma unroll
        for (int ct = 0; ct < 4; ++ct) acc[rt][ct] = (f32x4){0.f, 0.f, 0.f, 0.f};

    // idx for row rt*16+m, loaded redundantly by the 4 quads (cache broadcast)
    auto ldidx = [&](int k, int (&iv)[4]) {
#pragma unroll
        for (int rt = 0; rt < 4; ++rt) {
            int r = row0 + rt * 16 + m;
            iv[rt] = (r < Nout) ? nbr[(size_t)k * Nout + r] : tableN;
        }
    };
    auto ldA = [&](const int (&iv)[4], bf16x8 (&a)[4][KC]) {
#pragma unroll
        for (int rt = 0; rt < 4; ++rt) {
            const unsigned short* p = in + (size_t)iv[rt] * Cin + q * 8;
            const bool valid = iv[rt] < tableN;     // sentinel row read is safe (ws slack)
#pragma unroll
            for (int kc = 0; kc < KC; ++kc) {
                bf16x8 v = *(const bf16x8*)(p + kc * 32);
                a[rt][kc] = valid ? v : ZV;
            }
        }
    };
    auto ldB = [&](int k, bf16x8 (&b)[4][KC]) {
        const unsigned short* p = Wt + ((size_t)k * 64 + m) * Cin + q * 8;
#pragma unroll
        for (int ct = 0; ct < 4; ++ct)
#pragma unroll
            for (int kc = 0; kc < KC; ++kc)
                b[ct][kc] = *(const bf16x8*)(p + (size_t)ct * 16 * Cin + kc * 32);
    };

    if constexpr (PF) {
        // -------- pipelined path (Cin=64): frags double-buffered in regs
        int iv[2][4];
        bf16x8 a[2][4][KC], b[2][4][KC];
        ldidx(0, iv[0]);
        ldA(iv[0], a[0]);
        ldB(0, b[0]);
        if (K > 1) ldidx(1, iv[1]);
#pragma unroll
        for (int k = 0; k < K; ++k) {
            const int cur = k & 1, nxt = cur ^ 1;
            if (k + 2 < K) ldidx(k + 2, iv[cur]);   // iv[cur] (idx k) already consumed
            if (k + 1 < K) {
                ldA(iv[nxt], a[nxt]);               // idx k+1 arrived ~1 iter ago
                ldB(k + 1, b[nxt]);
            }
#pragma unroll
            for (int kc = 0; kc < KC; ++kc)
#pragma unroll
                for (int rt = 0; rt < 4; ++rt)
#pragma unroll
                    for (int ct = 0; ct < 4; ++ct)
                        acc[rt][ct] = __builtin_amdgcn_mfma_f32_16x16x32_bf16(
                            a[cur][rt][kc], b[cur][ct][kc], acc[rt][ct], 0, 0, 0);
        }
    } else {
        // -------- Cin=128: current-k frags only (reg budget), idx 2 ahead
        int ivc[4], ivn[4];
        ldidx(0, ivc);
        if (K > 1) ldidx(1, ivn);
        for (int k = 0; k < K; ++k) {
            bf16x8 a[4][KC], b[4][KC];
            ldA(ivc, a);
            ldB(k, b);
#pragma unroll
            for (int rt = 0; rt < 4; ++rt) ivc[rt] = ivn[rt];
            if (k + 2 < K) ldidx(k + 2, ivn);
#pragma unroll
            for (int kc = 0; kc < KC; ++kc)
#pragma unroll
                for (int rt = 0; rt < 4; ++rt)
#pragma unroll
                    for (int ct = 0; ct < 4; ++ct)
                        acc[rt][ct] = __builtin_amdgcn_mfma_f32_16x16x32_bf16(
                            a[rt][kc], b[ct][kc], acc[rt][ct], 0, 0, 0);
        }
    }

    // ---- epilogue: C/D layout col=lane&15 (n), row=q*4+reg (verified m89/m91)
    float psum[4] = {0.f, 0.f, 0.f, 0.f}, psq[4] = {0.f, 0.f, 0.f, 0.f};
#pragma unroll
    for (int rt = 0; rt < 4; ++rt) {
#pragma unroll
        for (int ct = 0; ct < 4; ++ct) {
            int col = ct * 16 + m;
#pragma unroll
            for (int reg = 0; reg < 4; ++reg) {
                int r = row0 + rt * 16 + q * 4 + reg;
                if (r < Nout) {
                    float v = acc[rt][ct][reg];
                    if (skip) v += skip[(size_t)r * 64 + col];
                    if (do_lrelu) v = (v >= 0.f) ? v : SLOPE * v;
                    if (out_bf) out_bf[(size_t)r * 64 + col] = f2bf(v);
                    else        out_f32[(size_t)r * 64 + col] = v;
                    psum[ct] += v;
                    psq[ct]  += v * v;
                }
            }
        }
    }

    if (stats) {
        // lanes m, m+16, m+32, m+48 share channel -> shuffle-reduce to q==0
#pragma unroll
        for (int ct = 0; ct < 4; ++ct) {
            psum[ct] += __shfl_down(psum[ct], 32);
            psum[ct] += __shfl_down(psum[ct], 16);
            psq[ct]  += __shfl_down(psq[ct], 32);
            psq[ct]  += __shfl_down(psq[ct], 16);
        }
        if (q == 0) {
#pragma unroll
            for (int ct = 0; ct < 4; ++ct) {
                red[0][ct * 16 + m][w] = psum[ct];
                red[1][ct * 16 + m][w] = psq[ct];
            }
        }
        __syncthreads();
        if (t < 64) {
            float s  = red[0][t][0] + red[0][t][1] + red[0][t][2] + red[0][t][3];
            float qq = red[1][t][0] + red[1][t][1] + red[1][t][2] + red[1][t][3];
            atomicAdd(&stats[t], s);
            atomicAdd(&stats[64 + t], qq);
        }
    }
}

// BN apply on bf16 buffer in-place.
__global__ __launch_bounds__(256)
void bn_apply_bf16(unsigned short* __restrict__ buf, size_t total8,
                   const float* __restrict__ stats,
                   const float* __restrict__ gamma,
                   const float* __restrict__ beta, float invN)
{
    __shared__ float sc[64], sh[64];
    int t = threadIdx.x;
    if (t < 64) {
        float mean = stats[t] * invN;
        float var  = stats[64 + t] * invN - mean * mean;
        float s    = gamma[t] * rsqrtf(var + EPS);
        sc[t] = s;
        sh[t] = beta[t] - mean * s;
    }
    __syncthreads();
    for (size_t i = (size_t)blockIdx.x * blockDim.x + t; i < total8;
         i += (size_t)gridDim.x * blockDim.x) {
        int4 v = ((const int4*)buf)[i];
        unsigned short* e = (unsigned short*)&v;
        int c0 = ((int)(i & 7)) << 3;
#pragma unroll
        for (int j = 0; j < 8; ++j)
            e[j] = f2bf(bf2f(e[j]) * sc[c0 + j] + sh[c0 + j]);
        ((int4*)buf)[i] = v;
    }
}

// BN apply fp32 in-place (final layer -> d_out).
__global__ __launch_bounds__(256)
void bn_apply_f32(float* __restrict__ buf, int N,
                  const float* __restrict__ stats,
                  const float* __restrict__ gamma,
                  const float* __restrict__ beta, float invN)
{
    __shared__ float sc[64], sh[64];
    int t = threadIdx.x;
    if (t < 64) {
        float mean = stats[t] * invN;
        float var  = stats[64 + t] * invN - mean * mean;
        float s    = gamma[t] * rsqrtf(var + EPS);
        sc[t] = s;
        sh[t] = beta[t] - mean * s;
    }
    __syncthreads();
    size_t total4 = (size_t)N * 16;
    for (size_t i = (size_t)blockIdx.x * blockDim.x + t; i < total4;
         i += (size_t)gridDim.x * blockDim.x) {
        float4 v = ((const float4*)buf)[i];
        int c0 = ((int)(i & 15)) << 2;
        v.x = v.x * sc[c0]     + sh[c0];
        v.y = v.y * sc[c0 + 1] + sh[c0 + 1];
        v.z = v.z * sc[c0 + 2] + sh[c0 + 2];
        v.w = v.w * sc[c0 + 3] + sh[c0 + 3];
        ((float4*)buf)[i] = v;
    }
}

// fp32 -> bf16 elementwise convert (x_feats).
__global__ __launch_bounds__(256)
void cvt_bf16(const float* __restrict__ in, unsigned short* __restrict__ out,
              size_t n4)
{
    for (size_t i = (size_t)blockIdx.x * blockDim.x + threadIdx.x; i < n4;
         i += (size_t)gridDim.x * blockDim.x) {
        float4 v = ((const float4*)in)[i];
        ushort4 o;
        o.x = f2bf(v.x); o.y = f2bf(v.y); o.z = f2bf(v.z); o.w = f2bf(v.w);
        ((ushort4*)out)[i] = o;
    }
}

static __device__ __forceinline__ void wt_one(int e, const float* __restrict__ W,
                                              unsigned short* __restrict__ Wt,
                                              int Cin)
{
    // e indexes Wt flat [k][d][c]
    int c = e % Cin;
    int rest = e / Cin;
    int d = rest & 63;
    int k = rest >> 6;
    Wt[e] = f2bf(W[((size_t)k * Cin + c) * 64 + d]);
}

// All 5 weight transposes ([K][Cin][64] f32 -> [K][64][Cin] bf16) in one launch.
__global__ __launch_bounds__(256)
void wt_cvt_all(const float* __restrict__ W_trans, const float* __restrict__ W_up,
                const float* __restrict__ W1, const float* __restrict__ W2,
                const float* __restrict__ W3,
                unsigned short* __restrict__ wt_t, unsigned short* __restrict__ wt_u,
                unsigned short* __restrict__ wt1, unsigned short* __restrict__ wt2,
                unsigned short* __restrict__ wt3)
{
    const int S0 = 27 * 128 * 64;            // trans
    const int S1 = 27 * 64 * 64;             // up
    const int S2 = 9 * 64 * 64;              // W1
    const int S3 = 9 * 64 * 64;              // W2
    const int S4 = 27 * 64 * 64;             // W3
    int e = blockIdx.x * blockDim.x + threadIdx.x;
    if (e < S0) { wt_one(e, W_trans, wt_t, 128); return; }
    e -= S0;
    if (e < S1) { wt_one(e, W_up, wt_u, 64); return; }
    e -= S1;
    if (e < S2) { wt_one(e, W1, wt1, 64); return; }
    e -= S2;
    if (e < S3) { wt_one(e, W2, wt2, 64); return; }
    e -= S3;
    if (e < S4) { wt_one(e, W3, wt3, 64); }
}

extern "C" void kernel_launch(void* const* d_in, const int* in_sizes, int n_in,
                              void* d_out, int out_size, void* d_ws, size_t ws_size,
                              hipStream_t stream) {
    const float* x_feats   = (const float*)d_in[0];
    const float* skip      = (const float*)d_in[1];
    const int*   nbr_trans = (const int*)d_in[2];
    const int*   nbr_up    = (const int*)d_in[3];
    const int*   nbr1      = (const int*)d_in[4];
    const int*   nbr2      = (const int*)d_in[5];
    const int*   nbr3      = (const int*)d_in[6];
    const float* W_trans   = (const float*)d_in[7];
    const float* W_up      = (const float*)d_in[8];
    const float* W1        = (const float*)d_in[9];
    const float* W2        = (const float*)d_in[10];
    const float* W3        = (const float*)d_in[11];
    const float* gamma_t   = (const float*)d_in[12];
    const float* beta_t    = (const float*)d_in[13];
    const float* gamma1    = (const float*)d_in[14];
    const float* beta1     = (const float*)d_in[15];
    const float* gamma2    = (const float*)d_in[16];
    const float* beta2     = (const float*)d_in[17];
    const float* gamma3    = (const float*)d_in[18];
    const float* beta3     = (const float*)d_in[19];

    const int Nin  = in_sizes[0] / 128;   // 80000
    const int Nout = in_sizes[1] / 64;    // 200000

    // ---- workspace layout. Gather tables first (each followed by more ws ->
    // reading sentinel row tableN is safe), stats last.
    size_t off = 0;
    auto alloc = [&](size_t bytes) {
        void* p = (char*)d_ws + off;
        off = (off + bytes + 255) & ~(size_t)255;
        return p;
    };
    unsigned short* xb   = (unsigned short*)alloc((size_t)Nin * 128 * 2);
    unsigned short* tb   = (unsigned short*)alloc((size_t)Nin * 64 * 2);
    unsigned short* ub   = (unsigned short*)alloc((size_t)Nout * 64 * 2);
    unsigned short* ab   = (unsigned short*)alloc((size_t)Nout * 64 * 2);
    unsigned short* vb   = (unsigned short*)alloc((size_t)Nout * 64 * 2);
    unsigned short* wt_t = (unsigned short*)alloc((size_t)27 * 128 * 64 * 2);
    unsigned short* wt_u = (unsigned short*)alloc((size_t)27 * 64 * 64 * 2);
    unsigned short* wt1  = (unsigned short*)alloc((size_t)9 * 64 * 64 * 2);
    unsigned short* wt2  = (unsigned short*)alloc((size_t)9 * 64 * 64 * 2);
    unsigned short* wt3  = (unsigned short*)alloc((size_t)27 * 64 * 64 * 2);
    float* stats = (float*)alloc(512 * sizeof(float));
    float* out   = (float*)d_out;

    hipMemsetAsync(stats, 0, 512 * sizeof(float), stream);

    dim3 blk(256);
    const float invNin  = 1.f / (float)Nin;
    const float invNout = 1.f / (float)Nout;

    wt_cvt_all<<<2016, blk, 0, stream>>>(W_trans, W_up, W1, W2, W3,
                                         wt_t, wt_u, wt1, wt2, wt3);
    cvt_bf16<<<2048, blk, 0, stream>>>(x_feats, xb, (size_t)Nin * 32);

    const int gIn  = (Nin  + 255) / 256;  // 313
    const int gOut = (Nout + 255) / 256;  // 782

    // trans_dilao: Cin=128, K=27 + LeakyReLU + BN
    conv_mfma<27, 2><<<gIn, blk, 0, stream>>>(xb, Nin, nbr_trans, Nin,
                                              wt_t, nullptr, tb, nullptr, stats + 0, 1);
    bn_apply_bf16<<<1024, blk, 0, stream>>>(tb, (size_t)Nin * 8, stats + 0,
                                            gamma_t, beta_t, invNin);
    // SparseInverseConv K=27 + skip (no act/bn)
    conv_mfma<27, 1><<<gOut, blk, 0, stream>>>(tb, Nin, nbr_up, Nout,
                                               wt_u, skip, ub, nullptr, nullptr, 0);
    // conv1 K=9 + LeakyReLU + BN
    conv_mfma<9, 1><<<gOut, blk, 0, stream>>>(ub, Nout, nbr1, Nout,
                                              wt1, nullptr, ab, nullptr, stats + 128, 1);
    bn_apply_bf16<<<2048, blk, 0, stream>>>(ab, (size_t)Nout * 8, stats + 128,
                                            gamma1, beta1, invNout);
    // conv2 K=9 + LeakyReLU + BN
    conv_mfma<9, 1><<<gOut, blk, 0, stream>>>(ab, Nout, nbr2, Nout,
                                              wt2, nullptr, vb, nullptr, stats + 256, 1);
    bn_apply_bf16<<<2048, blk, 0, stream>>>(vb, (size_t)Nout * 8, stats + 256,
                                            gamma2, beta2, invNout);
    // conv3 K=27 + LeakyReLU + BN -> d_out (fp32), normalize in place
    conv_mfma<27, 1><<<gOut, blk, 0, stream>>>(vb, Nout, nbr3, Nout,
                                               wt3, nullptr, nullptr, out, stats + 384, 1);
    bn_apply_f32<<<2048, blk, 0, stream>>>(out, Nout, stats + 384,
                                           gamma3, beta3, invNout);
}